// Round 10
// baseline (212.560 us; speedup 1.0000x reference)
//
#include <hip/hip_runtime.h>
#include <hip/hip_bf16.h>
#include <hip/hip_fp16.h>
#include <math.h>

#define NN 50000
#define NE 1600000
#define BSH 7           // 128 rows per bucket
#define BCK 391         // ceil(50000/128)
#define BCAP 5120       // per-bucket staging capacity (mean 4096, sigma ~64)
#define GEMM_BLKS 98    // fused kernel: blocks [0,98) gemm, [98,294) binA

typedef __attribute__((ext_vector_type(8))) short bf16x8;
typedef __attribute__((ext_vector_type(4))) float f32x4;
typedef __attribute__((ext_vector_type(2))) float f32x2;

__device__ __forceinline__ short f2bf(float f) {
    return (short)((__float_as_uint(f) + 0x8000u) >> 16);
}
__device__ __forceinline__ float lo16(unsigned u) { return __uint_as_float(u << 16); }
__device__ __forceinline__ float hi16(unsigned u) { return __uint_as_float(u & 0xffff0000u); }
__device__ __forceinline__ unsigned enc_f(float f) {
    unsigned u = __float_as_uint(f);
    return (u & 0x80000000u) ? ~u : (u | 0x80000000u);
}
__device__ __forceinline__ float dec_f(unsigned e) {
    return (e & 0x80000000u) ? __uint_as_float(e & 0x7FFFFFFFu)
                             : __uint_as_float(~e);
}

// ============ FUSED: layer0 GEMM (blocks [0,98)) + binA edge binning ([98,294)).
// Data-independent paths run concurrently. gcursor is RELATIVE (memset to 0);
// gemm path transposes W0 into LDS itself.
__global__ void __launch_bounds__(1024) gbinA_kernel(
        const float* __restrict__ X,
        const float* __restrict__ W0,
        const float* __restrict__ a,
        __hip_bfloat16* __restrict__ Hwb,
        float* __restrict__ pr,
        float* __restrict__ pc,
        unsigned* __restrict__ max0,
        const int* __restrict__ row, const int* __restrict__ col,
        int* __restrict__ gcursor, unsigned* __restrict__ staging) {
    __shared__ union SH {
        struct {
            unsigned lds_stage[8192];
            unsigned lds_addr[8192];
            int lds_cnt[512];
            int lds_off[512];
            int wg_goff[512];
            int wtot[8];
        } a;                                 // ~70 KB (binA path)
        struct {
            ushort Wt[64 * 264];
            unsigned bmax;
        } g;                                 // ~33 KB (gemm path)
    } sh;
    int tid = threadIdx.x;

    if (blockIdx.x < GEMM_BLKS) {
        // ---------------- gemm0 path: 4x 256-thread sub-groups ----------------
        if (tid == 0) sh.g.bmax = 0u;
        // transpose W0 [256][64] f32 -> Wt[n*264+k] bf16 (coalesced reads)
        for (int i = tid; i < 16384; i += 1024)
            sh.g.Wt[(i & 63) * 264 + (i >> 6)] = (ushort)f2bf(W0[i]);
        __syncthreads();
        int g256 = tid >> 8, t256 = tid & 255;
        int lane = t256 & 63, wid = t256 >> 6;
        int c = lane & 15, quad = lane >> 4;
        const ushort* wtp[4];
#pragma unroll
        for (int g = 0; g < 4; ++g) wtp[g] = &sh.g.Wt[(g * 16 + c) * 264 + quad * 8];
        float aA[4], aB[4];
#pragma unroll
        for (int g = 0; g < 4; ++g) { aA[g] = a[g * 16 + c]; aB[g] = a[64 + g * 16 + c]; }

        int row0 = blockIdx.x * 512 + g256 * 128 + wid * 16;
        float qmax = -1e30f;

#pragma unroll
        for (int tt = 0; tt < 2; ++tt) {
            int rt = row0 + tt * 64;
            int arow = rt + c; if (arow >= NN) arow = NN - 1;
            const float* xbase = X + (size_t)arow * 256 + quad * 8;
            f32x4 acc[4];
#pragma unroll
            for (int g = 0; g < 4; ++g) acc[g] = (f32x4){0.f, 0.f, 0.f, 0.f};

#pragma unroll
            for (int k0 = 0; k0 < 256; k0 += 32) {
                float4 xa = *(const float4*)(xbase + k0);
                float4 xb = *(const float4*)(xbase + k0 + 4);
                bf16x8 af;
                af[0] = f2bf(xa.x); af[1] = f2bf(xa.y); af[2] = f2bf(xa.z); af[3] = f2bf(xa.w);
                af[4] = f2bf(xb.x); af[5] = f2bf(xb.y); af[6] = f2bf(xb.z); af[7] = f2bf(xb.w);
#pragma unroll
                for (int g = 0; g < 4; ++g) {
                    bf16x8 bg = *(const bf16x8*)(wtp[g] + k0);
                    acc[g] = __builtin_amdgcn_mfma_f32_16x16x32_bf16(af, bg, acc[g], 0, 0, 0);
                }
            }

#pragma unroll
            for (int r = 0; r < 4; ++r) {
                int rr = rt + quad * 4 + r;
                float v0 = acc[0][r], v1 = acc[1][r], v2 = acc[2][r], v3 = acc[3][r];
                if (rr < NN) {
                    __hip_bfloat16* hp = Hwb + (size_t)rr * 64 + c;
                    hp[0]  = __float2bfloat16(v0);
                    hp[16] = __float2bfloat16(v1);
                    hp[32] = __float2bfloat16(v2);
                    hp[48] = __float2bfloat16(v3);
                }
                float pv = v0 * aA[0] + v1 * aA[1] + v2 * aA[2] + v3 * aA[3];
                float qv = v0 * aB[0] + v1 * aB[1] + v2 * aB[2] + v3 * aB[3];
#pragma unroll
                for (int off = 8; off; off >>= 1) {
                    pv += __shfl_xor(pv, off);
                    qv += __shfl_xor(qv, off);
                }
                if (c == 0 && rr < NN) { pr[rr] = pv; pc[rr] = qv; }
                if (rr < NN) qmax = fmaxf(qmax, qv);
            }
        }
        qmax = fmaxf(qmax, __shfl_xor(qmax, 16));
        qmax = fmaxf(qmax, __shfl_xor(qmax, 32));
        if (lane == 0) atomicMax(&sh.g.bmax, enc_f(qmax));
        __syncthreads();
        if (tid == 0) atomicMax(max0, sh.g.bmax);   // 98 blocks -> safe atomic count
        return;
    }

    // ---------------- binA path: bin 1.6M edges into 391 buckets ----------------
    int t = tid;
    int lane = t & 63;
    int w = t >> 6;
    int nbin = gridDim.x - GEMM_BLKS;       // 196

    for (int cb = (blockIdx.x - GEMM_BLKS) * 8192; cb < NE; cb += nbin * 8192) {
        int cnt_edges = NE - cb; if (cnt_edges > 8192) cnt_edges = 8192;
        if (t < 512) sh.a.lds_cnt[t] = 0;
        __syncthreads();
        int myb[8]; int mylo[8]; unsigned mypk[8];
        int e0 = cb + t * 8;
        if (t * 8 + 7 < cnt_edges) {
            int4 r0 = *(const int4*)(row + e0);
            int4 r1 = *(const int4*)(row + e0 + 4);
            int4 c0 = *(const int4*)(col + e0);
            int4 c1 = *(const int4*)(col + e0 + 4);
            int rr[8] = {r0.x, r0.y, r0.z, r0.w, r1.x, r1.y, r1.z, r1.w};
            int cc[8] = {c0.x, c0.y, c0.z, c0.w, c1.x, c1.y, c1.z, c1.w};
            #pragma unroll
            for (int i = 0; i < 8; ++i) {
                int b = rr[i] >> BSH;
                myb[i] = b;
                mypk[i] = ((unsigned)(rr[i] & 127) << 16) | (unsigned)cc[i];
                mylo[i] = atomicAdd(&sh.a.lds_cnt[b], 1);
            }
        } else {
            #pragma unroll
            for (int i = 0; i < 8; ++i) {
                int idx = t * 8 + i;
                myb[i] = -1;
                if (idx < cnt_edges) {
                    int e = cb + idx;
                    int r = row[e], c = col[e];
                    myb[i] = r >> BSH;
                    mypk[i] = ((unsigned)(r & 127) << 16) | (unsigned)c;
                    mylo[i] = atomicAdd(&sh.a.lds_cnt[myb[i]], 1);
                }
            }
        }
        __syncthreads();
        // 512-wide exclusive scan of bucket counts (8 waves + combine)
        int v = (t < 512) ? sh.a.lds_cnt[t] : 0;
        int x = v;
        #pragma unroll
        for (int off = 1; off < 64; off <<= 1) {
            int y = __shfl_up(x, off);
            if (lane >= off) x += y;
        }
        if (t < 512 && lane == 63) sh.a.wtot[w] = x;
        __syncthreads();
        if (t < 8) {
            int s = sh.a.wtot[t];
            #pragma unroll
            for (int off = 1; off < 8; off <<= 1) {
                int y = __shfl_up(s, off, 8);
                if ((t & 7) >= off) s += y;
            }
            sh.a.wtot[t] = s;   // inclusive wave prefix
        }
        __syncthreads();
        if (t < 512) {
            int add = (w > 0) ? sh.a.wtot[w - 1] : 0;
            sh.a.lds_off[t] = x - v + add;
        }
        if (t < BCK) {
            int cc2 = sh.a.lds_cnt[t];
            sh.a.wg_goff[t] = t * BCAP + (cc2 ? atomicAdd(&gcursor[t], cc2) : 0);
        }
        __syncthreads();
        #pragma unroll
        for (int i = 0; i < 8; ++i) if (myb[i] >= 0) {
            int p = sh.a.lds_off[myb[i]] + mylo[i];
            sh.a.lds_stage[p] = mypk[i];
            sh.a.lds_addr[p] = (unsigned)(sh.a.wg_goff[myb[i]] + mylo[i]);
        }
        __syncthreads();
        for (int i = t; i < cnt_edges; i += 1024)
            staging[sh.a.lds_addr[i]] = sh.a.lds_stage[i];
        __syncthreads();
    }
}

// Stage B: 391 blocks, 128 rows/bucket. NOW ALSO precomputes the layer-0
// attention weight per edge: w = exp(leakyrelu(pr[row]+pc[col]) - m[row]),
// stored fp16 alongside col: colperm2[i] = (col<<16) | fp16(w).
// Gathers pc0[col] are issued early (8/thread) and hide under the histogram.
__global__ void __launch_bounds__(1024) binB_kernel(
        const int* __restrict__ gcursor,
        const unsigned* __restrict__ staging,
        const float* __restrict__ pr0,
        const float* __restrict__ pc0,
        const unsigned* __restrict__ pcmax,
        int* __restrict__ rowptr,
        unsigned* __restrict__ colperm2) {
    __shared__ int bsc[512];    // bucket exclusive-scan partials
    __shared__ int bw[8];
    __shared__ int cur[128];
    __shared__ int wls2[2];
    __shared__ float pr_l[128];
    __shared__ float m_l[128];
    __shared__ unsigned lds_colw[BCAP];     // 20 KB
    int b = blockIdx.x;
    int t = threadIdx.x;
    int lane = t & 63;
    int w = t >> 6;

    // ---- bucket-level self-scan over 391 counts (8 waves + combine) ----
    if (t < 512) {
        int v = 0;
        if (t < BCK) {
            v = gcursor[t];
            if (v > BCAP) v = BCAP;
        }
        int x = v;
        #pragma unroll
        for (int off = 1; off < 64; off <<= 1) {
            int y = __shfl_up(x, off);
            if (lane >= off) x += y;
        }
        if (lane == 63) bw[w] = x;
        bsc[t] = x - v;
    }
    __syncthreads();
    if (t < 8) {
        int s = bw[t];
        #pragma unroll
        for (int off = 1; off < 8; off <<= 1) {
            int y = __shfl_up(s, off, 8);
            if ((t & 7) >= off) s += y;
        }
        bw[t] = s;   // inclusive wave prefix
    }
    __syncthreads();
    int gbase = bsc[b] + ((b >= 64) ? bw[(b >> 6) - 1] : 0);
    int cnt = gcursor[b];
    if (cnt > BCAP) cnt = BCAP;
    if (b == 0 && t == 0) rowptr[NN] = bw[7];
    int rbase = b << BSH;
    int nrows = NN - rbase; if (nrows > 128) nrows = 128;
    const unsigned* sb = staging + (size_t)b * BCAP;
    float pcm = dec_f(*pcmax);

    // per-row pr and softmax shift m
    if (t < 128) {
        int r = rbase + t;
        float pri = (r < NN) ? pr0[r] : 0.f;
        float mm = pri + pcm;
        mm = (mm >= 0.f) ? mm : 0.01f * mm;
        pr_l[t] = pri;
        m_l[t] = mm;
    }

    // ---- load staging into registers (coalesced uint4) ----
    unsigned ev[8];
    #pragma unroll
    for (int j = 0; j < 2; ++j) {
        int i0 = t * 4 + j * 4096;
        uint4 val = {0u, 0u, 0u, 0u};
        if (i0 + 3 < cnt) {
            val = *(const uint4*)(sb + i0);
        } else {
            if (i0 + 0 < cnt) val.x = sb[i0 + 0];
            if (i0 + 1 < cnt) val.y = sb[i0 + 1];
            if (i0 + 2 < cnt) val.z = sb[i0 + 2];
            if (i0 + 3 < cnt) val.w = sb[i0 + 3];
        }
        ev[j * 4 + 0] = val.x; ev[j * 4 + 1] = val.y;
        ev[j * 4 + 2] = val.z; ev[j * 4 + 3] = val.w;
    }

    // ---- issue scattered pc0 gathers early (hidden under histogram) ----
    float pcv[8];
    #pragma unroll
    for (int j = 0; j < 2; ++j) {
        #pragma unroll
        for (int l = 0; l < 4; ++l) {
            int idx = t * 4 + j * 4096 + l;
            int c = (idx < cnt) ? (int)(ev[j * 4 + l] & 0xffffu) : 0;
            pcv[j * 4 + l] = pc0[c];
        }
    }

    // ---- local histogram over 128 rows ----
    if (t < 128) cur[t] = 0;
    __syncthreads();
    #pragma unroll
    for (int j = 0; j < 2; ++j) {
        #pragma unroll
        for (int l = 0; l < 4; ++l) {
            int idx = t * 4 + j * 4096 + l;
            if (idx < cnt) atomicAdd(&cur[ev[j * 4 + l] >> 16], 1);
        }
    }
    __syncthreads();
    // ---- exclusive scan of 128 row-counts (2 waves) ----
    int v = 0, x = 0;
    if (t < 128) {
        v = cur[t];
        x = v;
        #pragma unroll
        for (int off = 1; off < 64; off <<= 1) {
            int y = __shfl_up(x, off);
            if (lane >= off) x += y;
        }
        if (lane == 63) wls2[w] = x;
    }
    __syncthreads();
    int excl = 0;
    if (t < 128) {
        excl = x - v + ((w == 1) ? wls2[0] : 0);
        if (t < nrows) rowptr[rbase + t] = gbase + excl;
    }
    __syncthreads();
    if (t < 128) cur[t] = excl;
    __syncthreads();
    // ---- compute fp16 weights + counting scatter into LDS ----
    #pragma unroll
    for (int j = 0; j < 2; ++j) {
        #pragma unroll
        for (int l = 0; l < 4; ++l) {
            int idx = t * 4 + j * 4096 + l;
            if (idx < cnt) {
                unsigned e = ev[j * 4 + l];
                int lr = (int)(e >> 16);
                float s = pr_l[lr] + pcv[j * 4 + l];
                s = (s >= 0.f) ? s : 0.01f * s;
                float wv = __expf(s - m_l[lr]);
                unsigned short w16 = __half_as_ushort(__float2half(wv));
                int pos = atomicAdd(&cur[lr], 1);
                lds_colw[pos] = ((e & 0xffffu) << 16) | (unsigned)w16;
            }
        }
    }
    __syncthreads();
    for (int i = t; i < cnt; i += 1024)
        colperm2[gbase + i] = lds_colw[i];
}

// ============ layer0 node kernel: weights PRECOMPUTED (fp16 in colperm2) —
// pure gather+FMA inner loop; no pc scatter, no exp, no LDS edge buffer.
// lane=(k 0..15 feature-quad, q 0..3 edge slot); 8B Hwb gather per lane.
// Fused gemm1 + 32-slot strided pc1-max.
__global__ void __launch_bounds__(256) node0_kernel(
        const int* __restrict__ rowptr,
        const unsigned* __restrict__ colperm2,
        const ushort* __restrict__ Hwb,
        const float* __restrict__ W1,
        const float* __restrict__ a1,
        __hip_bfloat16* __restrict__ Hw1b,
        float* __restrict__ pr1,
        float* __restrict__ pc1,
        unsigned* __restrict__ max1s) {
    __shared__ float W1s[64 * 17];
    __shared__ float a1s[32];
    __shared__ float hbuf[4][64];
    __shared__ unsigned bmax1;
    int t = threadIdx.x;
    if (t == 0) bmax1 = 0u;
    for (int i = t; i < 64 * 16; i += 256)
        W1s[(i >> 4) * 17 + (i & 15)] = W1[i];
    if (t < 32) a1s[t] = a1[t];
    __syncthreads();

    int lane = t & 63;
    int wid = t >> 6;
    int node = blockIdx.x * 4 + wid;        // grid exact: 12500*4 == NN
    int k = lane & 15, q = lane >> 4;
    int start = rowptr[node], end = rowptr[node + 1];
    int iters = (end - start + 3) >> 2;

    float wsum = 0.f;
    f32x2 accA = {0.f, 0.f}, accB = {0.f, 0.f};
    int e = start + q;
    const ushort* hb = Hwb + k * 4;
    #pragma unroll 4
    for (int jj = 0; jj < iters; ++jj, e += 4) {
        int idx = (e < end) ? e : start;
        unsigned ew = colperm2[idx];        // broadcast across the 16 k-lanes
        float wj = __half2float(__ushort_as_half((unsigned short)(ew & 0xffffu)));
        wj = (e < end) ? wj : 0.f;
        int cj = (int)(ew >> 16);
        uint2 hv = *(const uint2*)(hb + (size_t)cj * 64);
        wsum += wj;
        f32x2 wj2 = {wj, wj};
        accA += wj2 * (f32x2){lo16(hv.x), hi16(hv.x)};   // v_pk_fma_f32
        accB += wj2 * (f32x2){lo16(hv.y), hi16(hv.y)};
    }
    // wsum: each q-lane holds its slot's sum (duplicated across k); sum over q
    wsum += __shfl_xor(wsum, 16);
    wsum += __shfl_xor(wsum, 32);
    float acc0 = accA.x, acc1 = accA.y, acc2 = accB.x, acc3 = accB.y;
    acc0 += __shfl_xor(acc0, 16); acc0 += __shfl_xor(acc0, 32);
    acc1 += __shfl_xor(acc1, 16); acc1 += __shfl_xor(acc1, 32);
    acc2 += __shfl_xor(acc2, 16); acc2 += __shfl_xor(acc2, 32);
    acc3 += __shfl_xor(acc3, 16); acc3 += __shfl_xor(acc3, 32);

    float inv = (wsum > 0.f) ? 1.f / wsum : 0.f;
    float h0 = acc0 * inv; h0 = (h0 > 0.f) ? h0 : (__expf(h0) - 1.f);
    float h1 = acc1 * inv; h1 = (h1 > 0.f) ? h1 : (__expf(h1) - 1.f);
    float h2 = acc2 * inv; h2 = (h2 > 0.f) ? h2 : (__expf(h2) - 1.f);
    float h3 = acc3 * inv; h3 = (h3 > 0.f) ? h3 : (__expf(h3) - 1.f);
    if (q == 0) {
        float4 hh = {h0, h1, h2, h3};
        *(float4*)&hbuf[wid][k * 4] = hh;
    }
    // fused gemm1 (same-wave LDS produce->consume)
    int j = lane & 15, p = lane >> 4;
    const float* hbp = hbuf[wid];
    float vj = 0.f;
#pragma unroll
    for (int i = 0; i < 16; ++i) {
        int kk = p * 16 + i;
        vj = fmaf(hbp[kk], W1s[kk * 17 + j], vj);
    }
    vj += __shfl_xor(vj, 16);
    vj += __shfl_xor(vj, 32);
    if (p == 0) Hw1b[(size_t)node * 16 + j] = __float2bfloat16(vj);
    float pv = vj * a1s[j];
    float qv = vj * a1s[16 + j];
#pragma unroll
    for (int off = 8; off; off >>= 1) {
        pv += __shfl_xor(pv, off);
        qv += __shfl_xor(qv, off);
    }
    if (lane == 0) {
        pr1[node] = pv; pc1[node] = qv;
        atomicMax(&bmax1, enc_f(qv));
    }
    __syncthreads();
    // 32 slots x 64B stride: ~390 atomics per address (safe scale)
    if (t == 0) atomicMax(&max1s[(blockIdx.x & 31) * 16], bmax1);
}

// ============ layer1 node kernel (round-5 proven form, uint colperm):
// lane=(k 0..3 feature-quad, q 0..15 edge slot), 8B uint2 gather.
// Reduces the 32 pc1-max slots at entry.
__global__ void __launch_bounds__(256) node1_kernel(
        const int* __restrict__ rowptr,
        const unsigned* __restrict__ colperm2,
        const float* __restrict__ pr,
        const float* __restrict__ pc,
        const unsigned* __restrict__ max1s,
        const ushort* __restrict__ Hwb,
        float* __restrict__ out) {
    __shared__ unsigned long long wcbuf[4][64];
    __shared__ unsigned gmx;
    int t = threadIdx.x;
    if (t < 32) {
        unsigned v = max1s[t * 16];
        #pragma unroll
        for (int off = 16; off; off >>= 1) {
            unsigned o = (unsigned)__shfl_xor((int)v, off, 32);
            v = (v > o) ? v : o;
        }
        if (t == 0) gmx = v;
    }
    __syncthreads();
    int lane = t & 63;
    int wid = t >> 6;
    int node = blockIdx.x * 4 + wid;
    int k = lane & 3, q = lane >> 2;
    int start = rowptr[node], end = rowptr[node + 1];
    float pri = pr[node];
    float m = pri + dec_f(gmx);
    m = (m >= 0.f) ? m : 0.01f * m;

    float wsum = 0.f;
    f32x2 accA = {0.f, 0.f}, accB = {0.f, 0.f};
    for (int base = start; base < end; base += 64) {
        int n = end - base; if (n > 64) n = 64;
        float wv = 0.f; unsigned cv = 0;
        if (lane < n) {
            cv = colperm2[base + lane] >> 16;
            float s = pri + pc[cv];
            s = (s >= 0.f) ? s : 0.01f * s;
            wv = __expf(s - m);
        }
        wsum += wv;
        wcbuf[wid][lane] = ((unsigned long long)cv << 32) |
                           (unsigned long long)__float_as_uint(wv);
        int iters = (n + 15) >> 4;          // 16 edges per iteration
        #pragma unroll 4
        for (int jj = 0; jj < iters; ++jj) {
            unsigned long long wc = wcbuf[wid][jj * 16 + q];
            float wj = __uint_as_float((unsigned)wc);
            int cj = (int)(wc >> 32);
            uint2 hv = *(const uint2*)(Hwb + (size_t)cj * 16 + k * 4);
            f32x2 wj2 = {wj, wj};
            accA += wj2 * (f32x2){lo16(hv.x), hi16(hv.x)};
            accB += wj2 * (f32x2){lo16(hv.y), hi16(hv.y)};
        }
    }
#pragma unroll
    for (int off = 32; off; off >>= 1) wsum += __shfl_xor(wsum, off);
    float ac[4] = {accA.x, accA.y, accB.x, accB.y};
#pragma unroll
    for (int j4 = 0; j4 < 4; ++j4) {
        ac[j4] += __shfl_xor(ac[j4], 4);
        ac[j4] += __shfl_xor(ac[j4], 8);
        ac[j4] += __shfl_xor(ac[j4], 16);
        ac[j4] += __shfl_xor(ac[j4], 32);
    }
    float inv = (wsum > 0.f) ? 1.f / wsum : 0.f;
    float v0 = ac[0] * inv, v1 = ac[1] * inv;
    float v2 = ac[2] * inv, v3 = ac[3] * inv;
    // log_softmax over 16 feats: 4 local vals x width-4 butterflies over k lanes
    float mm = fmaxf(fmaxf(v0, v1), fmaxf(v2, v3));
    mm = fmaxf(mm, __shfl_xor(mm, 1, 4));
    mm = fmaxf(mm, __shfl_xor(mm, 2, 4));
    float ssx = __expf(v0 - mm) + __expf(v1 - mm) + __expf(v2 - mm) + __expf(v3 - mm);
    ssx += __shfl_xor(ssx, 1, 4);
    ssx += __shfl_xor(ssx, 2, 4);
    float lse = mm + __logf(ssx);
    if (q == 0) {
        float4 o = {v0 - lse, v1 - lse, v2 - lse, v3 - lse};
        *(float4*)(out + (size_t)node * 16 + k * 4) = o;
    }
}

extern "C" void kernel_launch(void* const* d_in, const int* in_sizes, int n_in,
                              void* d_out, int out_size, void* d_ws, size_t ws_size,
                              hipStream_t stream) {
    const float* X  = (const float*)d_in[0];
    const int*   ei = (const int*)d_in[1];
    const float* W0 = (const float*)d_in[2];
    const float* a0 = (const float*)d_in[3];
    const float* W1 = (const float*)d_in[4];
    const float* a1 = (const float*)d_in[5];
    float* out = (float*)d_out;

    const int* row = ei;
    const int* col = ei + NE;

    char* wsb = (char*)d_ws;
    size_t off = 0;
    auto alloc = [&](size_t bytes) {
        void* p = wsb + off;
        off += (bytes + 15) & ~(size_t)15;
        return p;
    };
    // zero-init region: maxes | max1s | gcursor (contiguous, one memset)
    unsigned* maxes = (unsigned*)alloc(16);             // [pcmax0]
    unsigned* max1s = (unsigned*)alloc(512 * 4);        // 32 slots x 64B stride
    int* gcursor    = (int*)alloc(512 * 4);             // 391 used (relative)
    size_t zinit = off;
    int* rowptr     = (int*)alloc((NN + 2) * 4);
    unsigned* staging = (unsigned*)alloc((size_t)BCK * BCAP * 4);
    unsigned* colperm2 = (unsigned*)alloc((size_t)NE * 4);
    __hip_bfloat16* Hw0b = (__hip_bfloat16*)alloc((size_t)NN * 64 * 2);
    float* pr0      = (float*)alloc(NN * 4);
    float* pc0      = (float*)alloc(NN * 4);
    __hip_bfloat16* Hw1b = (__hip_bfloat16*)alloc((size_t)NN * 16 * 2);
    float* pr1      = (float*)alloc(NN * 4);
    float* pc1      = (float*)alloc(NN * 4);

    hipMemsetAsync(wsb, 0, zinit, stream);

    // fused: layer0 GEMM (98 blocks) + binA edge binning (196 blocks)
    gbinA_kernel<<<GEMM_BLKS + 196, 1024, 0, stream>>>(X, W0, a0, Hw0b, pr0, pc0,
                                                       &maxes[0], row, col,
                                                       gcursor, staging);
    // binB: CSR build + fp16 layer-0 edge weights
    binB_kernel<<<BCK, 1024, 0, stream>>>(gcursor, staging, pr0, pc0, &maxes[0],
                                          rowptr, colperm2);

    // layer 0 (pure gather+FMA; fused layer-1 GEMM + 32-slot pc1-max)
    node0_kernel<<<NN / 4, 256, 0, stream>>>(rowptr, colperm2,
                                             (const ushort*)Hw0b,
                                             W1, a1, Hw1b, pr1, pc1, max1s);

    // layer 1 (reduces the 32 pc1-max slots at entry)
    node1_kernel<<<NN / 4, 256, 0, stream>>>(rowptr, colperm2, pr1, pc1,
                                             max1s, (const ushort*)Hw1b, out);
}

// Round 11
// 205.830 us; speedup vs baseline: 1.0327x; 1.0327x over previous
//
#include <hip/hip_runtime.h>
#include <hip/hip_bf16.h>
#include <math.h>

#define NN 50000
#define NE 1600000
#define BSH 7           // 128 rows per bucket
#define BCK 391         // ceil(50000/128)
#define BCAP 5120       // per-bucket staging capacity (mean 4096, sigma ~64)
#define GEMM_BLKS 98    // fused kernel: blocks [0,98) gemm, [98,294) binA

typedef __attribute__((ext_vector_type(8))) short bf16x8;
typedef __attribute__((ext_vector_type(4))) float f32x4;
typedef __attribute__((ext_vector_type(2))) float f32x2;

__device__ __forceinline__ short f2bf(float f) {
    return (short)((__float_as_uint(f) + 0x8000u) >> 16);
}
__device__ __forceinline__ float lo16(unsigned u) { return __uint_as_float(u << 16); }
__device__ __forceinline__ float hi16(unsigned u) { return __uint_as_float(u & 0xffff0000u); }
__device__ __forceinline__ unsigned enc_f(float f) {
    unsigned u = __float_as_uint(f);
    return (u & 0x80000000u) ? ~u : (u | 0x80000000u);
}
__device__ __forceinline__ float dec_f(unsigned e) {
    return (e & 0x80000000u) ? __uint_as_float(e & 0x7FFFFFFFu)
                             : __uint_as_float(~e);
}

// ============ FUSED: layer0 GEMM (blocks [0,98)) + binA edge binning ([98,294)).
// Data-independent paths run concurrently. gcursor is RELATIVE (memset to 0);
// gemm path transposes W0 into LDS itself (setup kernel eliminated).
__global__ void __launch_bounds__(1024) gbinA_kernel(
        const float* __restrict__ X,
        const float* __restrict__ W0,
        const float* __restrict__ a,
        __hip_bfloat16* __restrict__ Hwb,
        float* __restrict__ pr,
        float* __restrict__ pc,
        unsigned* __restrict__ max0,
        const int* __restrict__ row, const int* __restrict__ col,
        int* __restrict__ gcursor, unsigned* __restrict__ staging) {
    __shared__ union SH {
        struct {
            unsigned lds_stage[8192];
            unsigned lds_addr[8192];
            int lds_cnt[512];
            int lds_off[512];
            int wg_goff[512];
            int wtot[8];
        } a;                                 // ~70 KB (binA path)
        struct {
            ushort Wt[64 * 264];
            unsigned bmax;
        } g;                                 // ~33 KB (gemm path)
    } sh;
    int tid = threadIdx.x;

    if (blockIdx.x < GEMM_BLKS) {
        // ---------------- gemm0 path: 4x 256-thread sub-groups ----------------
        if (tid == 0) sh.g.bmax = 0u;
        // transpose W0 [256][64] f32 -> Wt[n*264+k] bf16 (coalesced reads)
        for (int i = tid; i < 16384; i += 1024)
            sh.g.Wt[(i & 63) * 264 + (i >> 6)] = (ushort)f2bf(W0[i]);
        __syncthreads();
        int g256 = tid >> 8, t256 = tid & 255;
        int lane = t256 & 63, wid = t256 >> 6;
        int c = lane & 15, quad = lane >> 4;
        const ushort* wtp[4];
#pragma unroll
        for (int g = 0; g < 4; ++g) wtp[g] = &sh.g.Wt[(g * 16 + c) * 264 + quad * 8];
        float aA[4], aB[4];
#pragma unroll
        for (int g = 0; g < 4; ++g) { aA[g] = a[g * 16 + c]; aB[g] = a[64 + g * 16 + c]; }

        int row0 = blockIdx.x * 512 + g256 * 128 + wid * 16;
        float qmax = -1e30f;

#pragma unroll
        for (int tt = 0; tt < 2; ++tt) {
            int rt = row0 + tt * 64;
            int arow = rt + c; if (arow >= NN) arow = NN - 1;
            const float* xbase = X + (size_t)arow * 256 + quad * 8;
            f32x4 acc[4];
#pragma unroll
            for (int g = 0; g < 4; ++g) acc[g] = (f32x4){0.f, 0.f, 0.f, 0.f};

#pragma unroll
            for (int k0 = 0; k0 < 256; k0 += 32) {
                float4 xa = *(const float4*)(xbase + k0);
                float4 xb = *(const float4*)(xbase + k0 + 4);
                bf16x8 af;
                af[0] = f2bf(xa.x); af[1] = f2bf(xa.y); af[2] = f2bf(xa.z); af[3] = f2bf(xa.w);
                af[4] = f2bf(xb.x); af[5] = f2bf(xb.y); af[6] = f2bf(xb.z); af[7] = f2bf(xb.w);
#pragma unroll
                for (int g = 0; g < 4; ++g) {
                    bf16x8 bg = *(const bf16x8*)(wtp[g] + k0);
                    acc[g] = __builtin_amdgcn_mfma_f32_16x16x32_bf16(af, bg, acc[g], 0, 0, 0);
                }
            }

#pragma unroll
            for (int r = 0; r < 4; ++r) {
                int rr = rt + quad * 4 + r;
                float v0 = acc[0][r], v1 = acc[1][r], v2 = acc[2][r], v3 = acc[3][r];
                if (rr < NN) {
                    __hip_bfloat16* hp = Hwb + (size_t)rr * 64 + c;
                    hp[0]  = __float2bfloat16(v0);
                    hp[16] = __float2bfloat16(v1);
                    hp[32] = __float2bfloat16(v2);
                    hp[48] = __float2bfloat16(v3);
                }
                float pv = v0 * aA[0] + v1 * aA[1] + v2 * aA[2] + v3 * aA[3];
                float qv = v0 * aB[0] + v1 * aB[1] + v2 * aB[2] + v3 * aB[3];
#pragma unroll
                for (int off = 8; off; off >>= 1) {
                    pv += __shfl_xor(pv, off);
                    qv += __shfl_xor(qv, off);
                }
                if (c == 0 && rr < NN) { pr[rr] = pv; pc[rr] = qv; }
                if (rr < NN) qmax = fmaxf(qmax, qv);
            }
        }
        qmax = fmaxf(qmax, __shfl_xor(qmax, 16));
        qmax = fmaxf(qmax, __shfl_xor(qmax, 32));
        if (lane == 0) atomicMax(&sh.g.bmax, enc_f(qmax));
        __syncthreads();
        if (tid == 0) atomicMax(max0, sh.g.bmax);   // 98 blocks -> safe atomic count
        return;
    }

    // ---------------- binA path: bin 1.6M edges into 391 buckets ----------------
    int t = tid;
    int lane = t & 63;
    int w = t >> 6;
    int nbin = gridDim.x - GEMM_BLKS;       // 196

    for (int cb = (blockIdx.x - GEMM_BLKS) * 8192; cb < NE; cb += nbin * 8192) {
        int cnt_edges = NE - cb; if (cnt_edges > 8192) cnt_edges = 8192;
        if (t < 512) sh.a.lds_cnt[t] = 0;
        __syncthreads();
        int myb[8]; int mylo[8]; unsigned mypk[8];
        int e0 = cb + t * 8;
        if (t * 8 + 7 < cnt_edges) {
            int4 r0 = *(const int4*)(row + e0);
            int4 r1 = *(const int4*)(row + e0 + 4);
            int4 c0 = *(const int4*)(col + e0);
            int4 c1 = *(const int4*)(col + e0 + 4);
            int rr[8] = {r0.x, r0.y, r0.z, r0.w, r1.x, r1.y, r1.z, r1.w};
            int cc[8] = {c0.x, c0.y, c0.z, c0.w, c1.x, c1.y, c1.z, c1.w};
            #pragma unroll
            for (int i = 0; i < 8; ++i) {
                int b = rr[i] >> BSH;
                myb[i] = b;
                mypk[i] = ((unsigned)(rr[i] & 127) << 16) | (unsigned)cc[i];
                mylo[i] = atomicAdd(&sh.a.lds_cnt[b], 1);
            }
        } else {
            #pragma unroll
            for (int i = 0; i < 8; ++i) {
                int idx = t * 8 + i;
                myb[i] = -1;
                if (idx < cnt_edges) {
                    int e = cb + idx;
                    int r = row[e], c = col[e];
                    myb[i] = r >> BSH;
                    mypk[i] = ((unsigned)(r & 127) << 16) | (unsigned)c;
                    mylo[i] = atomicAdd(&sh.a.lds_cnt[myb[i]], 1);
                }
            }
        }
        __syncthreads();
        // 512-wide exclusive scan of bucket counts (8 waves + combine)
        int v = (t < 512) ? sh.a.lds_cnt[t] : 0;
        int x = v;
        #pragma unroll
        for (int off = 1; off < 64; off <<= 1) {
            int y = __shfl_up(x, off);
            if (lane >= off) x += y;
        }
        if (t < 512 && lane == 63) sh.a.wtot[w] = x;
        __syncthreads();
        if (t < 8) {
            int s = sh.a.wtot[t];
            #pragma unroll
            for (int off = 1; off < 8; off <<= 1) {
                int y = __shfl_up(s, off, 8);
                if ((t & 7) >= off) s += y;
            }
            sh.a.wtot[t] = s;   // inclusive wave prefix
        }
        __syncthreads();
        if (t < 512) {
            int add = (w > 0) ? sh.a.wtot[w - 1] : 0;
            sh.a.lds_off[t] = x - v + add;
        }
        if (t < BCK) {
            int cc2 = sh.a.lds_cnt[t];
            sh.a.wg_goff[t] = t * BCAP + (cc2 ? atomicAdd(&gcursor[t], cc2) : 0);
        }
        __syncthreads();
        #pragma unroll
        for (int i = 0; i < 8; ++i) if (myb[i] >= 0) {
            int p = sh.a.lds_off[myb[i]] + mylo[i];
            sh.a.lds_stage[p] = mypk[i];
            sh.a.lds_addr[p] = (unsigned)(sh.a.wg_goff[myb[i]] + mylo[i]);
        }
        __syncthreads();
        for (int i = t; i < cnt_edges; i += 1024)
            staging[sh.a.lds_addr[i]] = sh.a.lds_stage[i];
        __syncthreads();
    }
}

// Stage B: 391 blocks (1.5/CU), 128 rows/bucket.
__global__ void __launch_bounds__(1024) binB_kernel(
        const int* __restrict__ gcursor,
        const unsigned* __restrict__ staging,
        int* __restrict__ rowptr,
        ushort* __restrict__ colperm) {
    __shared__ int bsc[512];    // bucket exclusive-scan partials
    __shared__ int bw[8];
    __shared__ int cur[128];
    __shared__ int wls2[2];
    __shared__ ushort lds_col[BCAP];
    int b = blockIdx.x;
    int t = threadIdx.x;
    int lane = t & 63;
    int w = t >> 6;

    // ---- bucket-level self-scan over 391 counts (8 waves + combine) ----
    if (t < 512) {
        int v = 0;
        if (t < BCK) {
            v = gcursor[t];
            if (v > BCAP) v = BCAP;
        }
        int x = v;
        #pragma unroll
        for (int off = 1; off < 64; off <<= 1) {
            int y = __shfl_up(x, off);
            if (lane >= off) x += y;
        }
        if (lane == 63) bw[w] = x;
        bsc[t] = x - v;
    }
    __syncthreads();
    if (t < 8) {
        int s = bw[t];
        #pragma unroll
        for (int off = 1; off < 8; off <<= 1) {
            int y = __shfl_up(s, off, 8);
            if ((t & 7) >= off) s += y;
        }
        bw[t] = s;   // inclusive wave prefix
    }
    __syncthreads();
    int gbase = bsc[b] + ((b >= 64) ? bw[(b >> 6) - 1] : 0);
    int cnt = gcursor[b];
    if (cnt > BCAP) cnt = BCAP;
    if (b == 0 && t == 0) rowptr[NN] = bw[7];
    int rbase = b << BSH;
    int nrows = NN - rbase; if (nrows > 128) nrows = 128;
    const unsigned* sb = staging + (size_t)b * BCAP;

    // ---- load staging into registers (coalesced uint4) ----
    unsigned ev[8];
    #pragma unroll
    for (int j = 0; j < 2; ++j) {
        int i0 = t * 4 + j * 4096;
        uint4 val = {0u, 0u, 0u, 0u};
        if (i0 + 3 < cnt) {
            val = *(const uint4*)(sb + i0);
        } else {
            if (i0 + 0 < cnt) val.x = sb[i0 + 0];
            if (i0 + 1 < cnt) val.y = sb[i0 + 1];
            if (i0 + 2 < cnt) val.z = sb[i0 + 2];
            if (i0 + 3 < cnt) val.w = sb[i0 + 3];
        }
        ev[j * 4 + 0] = val.x; ev[j * 4 + 1] = val.y;
        ev[j * 4 + 2] = val.z; ev[j * 4 + 3] = val.w;
    }

    // ---- local histogram over 128 rows ----
    if (t < 128) cur[t] = 0;
    __syncthreads();
    #pragma unroll
    for (int j = 0; j < 2; ++j) {
        #pragma unroll
        for (int l = 0; l < 4; ++l) {
            int idx = t * 4 + j * 4096 + l;
            if (idx < cnt) atomicAdd(&cur[ev[j * 4 + l] >> 16], 1);
        }
    }
    __syncthreads();
    // ---- exclusive scan of 128 row-counts (2 waves) ----
    int v = 0, x = 0;
    if (t < 128) {
        v = cur[t];
        x = v;
        #pragma unroll
        for (int off = 1; off < 64; off <<= 1) {
            int y = __shfl_up(x, off);
            if (lane >= off) x += y;
        }
        if (lane == 63) wls2[w] = x;
    }
    __syncthreads();
    int excl = 0;
    if (t < 128) {
        excl = x - v + ((w == 1) ? wls2[0] : 0);
        if (t < nrows) rowptr[rbase + t] = gbase + excl;
    }
    __syncthreads();
    if (t < 128) cur[t] = excl;
    __syncthreads();
    // ---- counting scatter from registers into LDS ----
    #pragma unroll
    for (int j = 0; j < 2; ++j) {
        #pragma unroll
        for (int l = 0; l < 4; ++l) {
            int idx = t * 4 + j * 4096 + l;
            if (idx < cnt) {
                unsigned e = ev[j * 4 + l];
                int pos = atomicAdd(&cur[e >> 16], 1);
                lds_col[pos] = (ushort)(e & 0xFFFFu);
            }
        }
    }
    __syncthreads();
    for (int i = t; i < cnt; i += 1024)
        colperm[gbase + i] = lds_col[i];
}

// ============ layer0 node kernel (round-5 proven form): fused gemm1,
// lane=(k 0..15 feature-quad, q 0..3 edge slot); 8B gather per lane.
// + 32-slot strided pc1-max.
__global__ void __launch_bounds__(256) node0_kernel(
        const int* __restrict__ rowptr,
        const ushort* __restrict__ colperm,
        const float* __restrict__ pr,
        const float* __restrict__ pc,
        const unsigned* __restrict__ pcmax,
        const ushort* __restrict__ Hwb,
        const float* __restrict__ W1,
        const float* __restrict__ a1,
        __hip_bfloat16* __restrict__ Hw1b,
        float* __restrict__ pr1,
        float* __restrict__ pc1,
        unsigned* __restrict__ max1s) {
    __shared__ float W1s[64 * 17];
    __shared__ float a1s[32];
    __shared__ float hbuf[4][64];
    __shared__ unsigned long long wcbuf[4][64];
    __shared__ unsigned bmax1;
    int t = threadIdx.x;
    if (t == 0) bmax1 = 0u;
    for (int i = t; i < 64 * 16; i += 256)
        W1s[(i >> 4) * 17 + (i & 15)] = W1[i];
    if (t < 32) a1s[t] = a1[t];
    __syncthreads();

    int lane = t & 63;
    int wid = t >> 6;
    int node = blockIdx.x * 4 + wid;        // grid exact: 12500*4 == NN
    int k = lane & 15, q = lane >> 4;
    int start = rowptr[node], end = rowptr[node + 1];
    float pri = pr[node];
    float m = pri + dec_f(*pcmax);
    m = (m >= 0.f) ? m : 0.01f * m;

    float wsum = 0.f;
    f32x2 accA = {0.f, 0.f}, accB = {0.f, 0.f};
    for (int base = start; base < end; base += 64) {
        int n = end - base; if (n > 64) n = 64;
        float wv = 0.f; unsigned cv = 0;
        if (lane < n) {
            cv = (unsigned)colperm[base + lane];
            float s = pri + pc[cv];
            s = (s >= 0.f) ? s : 0.01f * s;
            wv = __expf(s - m);
        }
        wsum += wv;
        wcbuf[wid][lane] = ((unsigned long long)cv << 32) |
                           (unsigned long long)__float_as_uint(wv);
        int iters = (n + 3) >> 2;   // j = jj*4+q <= 63 always
        #pragma unroll 4
        for (int jj = 0; jj < iters; ++jj) {
            unsigned long long wc = wcbuf[wid][jj * 4 + q];
            float wj = __uint_as_float((unsigned)wc);
            int cj = (int)(wc >> 32);
            uint2 hv = *(const uint2*)(Hwb + (size_t)cj * 64 + k * 4);
            f32x2 wj2 = {wj, wj};
            f32x2 h01 = {lo16(hv.x), hi16(hv.x)};
            f32x2 h23 = {lo16(hv.y), hi16(hv.y)};
            accA += wj2 * h01;     // v_pk_fma_f32
            accB += wj2 * h23;
        }
    }
#pragma unroll
    for (int off = 32; off; off >>= 1) wsum += __shfl_xor(wsum, off);
    float acc0 = accA.x, acc1 = accA.y, acc2 = accB.x, acc3 = accB.y;
    acc0 += __shfl_xor(acc0, 16); acc0 += __shfl_xor(acc0, 32);
    acc1 += __shfl_xor(acc1, 16); acc1 += __shfl_xor(acc1, 32);
    acc2 += __shfl_xor(acc2, 16); acc2 += __shfl_xor(acc2, 32);
    acc3 += __shfl_xor(acc3, 16); acc3 += __shfl_xor(acc3, 32);

    float inv = (wsum > 0.f) ? 1.f / wsum : 0.f;
    float h0 = acc0 * inv; h0 = (h0 > 0.f) ? h0 : (__expf(h0) - 1.f);
    float h1 = acc1 * inv; h1 = (h1 > 0.f) ? h1 : (__expf(h1) - 1.f);
    float h2 = acc2 * inv; h2 = (h2 > 0.f) ? h2 : (__expf(h2) - 1.f);
    float h3 = acc3 * inv; h3 = (h3 > 0.f) ? h3 : (__expf(h3) - 1.f);
    if (q == 0) {
        float4 hh = {h0, h1, h2, h3};
        *(float4*)&hbuf[wid][k * 4] = hh;
    }
    // fused gemm1 (same-wave LDS produce->consume)
    int j = lane & 15, p = lane >> 4;
    const float* hbp = hbuf[wid];
    float vj = 0.f;
#pragma unroll
    for (int i = 0; i < 16; ++i) {
        int kk = p * 16 + i;
        vj = fmaf(hbp[kk], W1s[kk * 17 + j], vj);
    }
    vj += __shfl_xor(vj, 16);
    vj += __shfl_xor(vj, 32);
    if (p == 0) Hw1b[(size_t)node * 16 + j] = __float2bfloat16(vj);
    float pv = vj * a1s[j];
    float qv = vj * a1s[16 + j];
#pragma unroll
    for (int off = 8; off; off >>= 1) {
        pv += __shfl_xor(pv, off);
        qv += __shfl_xor(qv, off);
    }
    if (lane == 0) {
        pr1[node] = pv; pc1[node] = qv;
        atomicMax(&bmax1, enc_f(qv));
    }
    __syncthreads();
    // 32 slots x 64B stride: ~390 atomics per address (safe scale)
    if (t == 0) atomicMax(&max1s[(blockIdx.x & 31) * 16], bmax1);
}

// ============ layer1 node kernel: lane=(k 0..3 feature-quad, q 0..15 edge slot),
// 8B uint2 gather -> 16 edges/iter. Reduces the 32 pc1-max slots at entry.
__global__ void __launch_bounds__(256) node1_kernel(
        const int* __restrict__ rowptr,
        const ushort* __restrict__ colperm,
        const float* __restrict__ pr,
        const float* __restrict__ pc,
        const unsigned* __restrict__ max1s,
        const ushort* __restrict__ Hwb,
        float* __restrict__ out) {
    __shared__ unsigned long long wcbuf[4][64];
    __shared__ unsigned gmx;
    int t = threadIdx.x;
    if (t < 32) {
        unsigned v = max1s[t * 16];
        #pragma unroll
        for (int off = 16; off; off >>= 1) {
            unsigned o = (unsigned)__shfl_xor((int)v, off, 32);
            v = (v > o) ? v : o;
        }
        if (t == 0) gmx = v;
    }
    __syncthreads();
    int lane = t & 63;
    int wid = t >> 6;
    int node = blockIdx.x * 4 + wid;
    int k = lane & 3, q = lane >> 2;
    int start = rowptr[node], end = rowptr[node + 1];
    float pri = pr[node];
    float m = pri + dec_f(gmx);
    m = (m >= 0.f) ? m : 0.01f * m;

    float wsum = 0.f;
    f32x2 accA = {0.f, 0.f}, accB = {0.f, 0.f};
    for (int base = start; base < end; base += 64) {
        int n = end - base; if (n > 64) n = 64;
        float wv = 0.f; unsigned cv = 0;
        if (lane < n) {
            cv = (unsigned)colperm[base + lane];
            float s = pri + pc[cv];
            s = (s >= 0.f) ? s : 0.01f * s;
            wv = __expf(s - m);
        }
        wsum += wv;
        wcbuf[wid][lane] = ((unsigned long long)cv << 32) |
                           (unsigned long long)__float_as_uint(wv);
        int iters = (n + 15) >> 4;          // 16 edges per iteration
        #pragma unroll 4
        for (int jj = 0; jj < iters; ++jj) {
            unsigned long long wc = wcbuf[wid][jj * 16 + q];
            float wj = __uint_as_float((unsigned)wc);
            int cj = (int)(wc >> 32);
            uint2 hv = *(const uint2*)(Hwb + (size_t)cj * 16 + k * 4);
            f32x2 wj2 = {wj, wj};
            accA += wj2 * (f32x2){lo16(hv.x), hi16(hv.x)};
            accB += wj2 * (f32x2){lo16(hv.y), hi16(hv.y)};
        }
    }
#pragma unroll
    for (int off = 32; off; off >>= 1) wsum += __shfl_xor(wsum, off);
    float ac[4] = {accA.x, accA.y, accB.x, accB.y};
#pragma unroll
    for (int j4 = 0; j4 < 4; ++j4) {
        ac[j4] += __shfl_xor(ac[j4], 4);
        ac[j4] += __shfl_xor(ac[j4], 8);
        ac[j4] += __shfl_xor(ac[j4], 16);
        ac[j4] += __shfl_xor(ac[j4], 32);
    }
    float inv = (wsum > 0.f) ? 1.f / wsum : 0.f;
    float v0 = ac[0] * inv, v1 = ac[1] * inv;
    float v2 = ac[2] * inv, v3 = ac[3] * inv;
    // log_softmax over 16 feats: 4 local vals x width-4 butterflies over k lanes
    float mm = fmaxf(fmaxf(v0, v1), fmaxf(v2, v3));
    mm = fmaxf(mm, __shfl_xor(mm, 1, 4));
    mm = fmaxf(mm, __shfl_xor(mm, 2, 4));
    float ssx = __expf(v0 - mm) + __expf(v1 - mm) + __expf(v2 - mm) + __expf(v3 - mm);
    ssx += __shfl_xor(ssx, 1, 4);
    ssx += __shfl_xor(ssx, 2, 4);
    float lse = mm + __logf(ssx);
    if (q == 0) {
        float4 o = {v0 - lse, v1 - lse, v2 - lse, v3 - lse};
        *(float4*)(out + (size_t)node * 16 + k * 4) = o;
    }
}

extern "C" void kernel_launch(void* const* d_in, const int* in_sizes, int n_in,
                              void* d_out, int out_size, void* d_ws, size_t ws_size,
                              hipStream_t stream) {
    const float* X  = (const float*)d_in[0];
    const int*   ei = (const int*)d_in[1];
    const float* W0 = (const float*)d_in[2];
    const float* a0 = (const float*)d_in[3];
    const float* W1 = (const float*)d_in[4];
    const float* a1 = (const float*)d_in[5];
    float* out = (float*)d_out;

    const int* row = ei;
    const int* col = ei + NE;

    char* wsb = (char*)d_ws;
    size_t off = 0;
    auto alloc = [&](size_t bytes) {
        void* p = wsb + off;
        off += (bytes + 15) & ~(size_t)15;
        return p;
    };
    // zero-init region: maxes | max1s | gcursor (contiguous, one memset)
    unsigned* maxes = (unsigned*)alloc(16);             // [pcmax0]
    unsigned* max1s = (unsigned*)alloc(512 * 4);        // 32 slots x 64B stride
    int* gcursor    = (int*)alloc(512 * 4);             // 391 used (relative)
    size_t zinit = off;
    int* rowptr     = (int*)alloc((NN + 2) * 4);
    unsigned* staging = (unsigned*)alloc((size_t)BCK * BCAP * 4);
    ushort* colperm = (ushort*)alloc((size_t)NE * 2);
    __hip_bfloat16* Hw0b = (__hip_bfloat16*)alloc((size_t)NN * 64 * 2);
    float* pr0      = (float*)alloc(NN * 4);
    float* pc0      = (float*)alloc(NN * 4);
    __hip_bfloat16* Hw1b = (__hip_bfloat16*)alloc((size_t)NN * 16 * 2);
    float* pr1      = (float*)alloc(NN * 4);
    float* pc1      = (float*)alloc(NN * 4);

    hipMemsetAsync(wsb, 0, zinit, stream);

    // fused: layer0 GEMM (98 blocks) + binA edge binning (196 blocks)
    gbinA_kernel<<<GEMM_BLKS + 196, 1024, 0, stream>>>(X, W0, a0, Hw0b, pr0, pc0,
                                                       &maxes[0], row, col,
                                                       gcursor, staging);
    binB_kernel<<<BCK, 1024, 0, stream>>>(gcursor, staging, rowptr, colperm);

    // layer 0 (+ fused layer-1 GEMM + fused pc0-max + 32-slot pc1-max)
    node0_kernel<<<NN / 4, 256, 0, stream>>>(rowptr, colperm, pr0, pc0,
                                             &maxes[0], (const ushort*)Hw0b,
                                             W1, a1, Hw1b, pr1, pc1, max1s);

    // layer 1 (reduces the 32 pc1-max slots at entry)
    node1_kernel<<<NN / 4, 256, 0, stream>>>(rowptr, colperm, pr1, pc1,
                                             max1s, (const ushort*)Hw1b, out);
}